// Round 11
// baseline (131.516 us; speedup 1.0000x reference)
//
#include <hip/hip_runtime.h>
#include <stdint.h>

#define EPSN 1e-12f

typedef float f32x16 __attribute__((ext_vector_type(16)));
typedef float f32x4 __attribute__((ext_vector_type(4)));
typedef __bf16 bf16x8 __attribute__((ext_vector_type(8)));

// ---- bf16 helpers (round-to-nearest-even) ----
__device__ __forceinline__ unsigned short f2bf(float f) {
  union { float f; unsigned int u; } v; v.f = f;
  unsigned int u = v.u + 0x7FFFu + ((v.u >> 16) & 1u);
  return (unsigned short)(u >> 16);
}

// async global->LDS DMA, 16B per lane; LDS dest wave-uniform base.
__device__ __forceinline__ void dma16(const void* g, void* l) {
  __builtin_amdgcn_global_load_lds(
      (const __attribute__((address_space(1))) unsigned int*)g,
      (__attribute__((address_space(3))) unsigned int*)l, 16, 0, 0);
}

// ---- workspace layout (ushort offsets) ----
// Fragment-major packed weights for 32x32x16 MFMA:
//   addr = ((tile*18 + ks)*64 + hi*32 + col)*8 + j
//   value = W[o = tile*32 + col][k = ks*16 + hi*8 + j]  (k=258 bias, >258 zero)
#define WQF_OFF 0
#define WKF_OFF (32 * 18 * 64 * 8)
#define WVP_OFF (2 * 32 * 18 * 64 * 8)

// =====================================================================
// prep (R10 version — fast, keep): coalesced pack + parallel WVt
// =====================================================================
__global__ __launch_bounds__(256) void prep_kernel(
    const float* __restrict__ wq, const float* __restrict__ bq,
    const float* __restrict__ wk, const float* __restrict__ bk,
    const float* __restrict__ v, const float* __restrict__ wout,
    unsigned short* __restrict__ wsp) {
  int bid = blockIdx.x;
  if (bid < 512) {
    int isK = bid >= 256;
    int ob = (bid & 255) * 4;
    const float* w = isK ? wk : wq;
    const float* bb = isK ? bk : bq;
    unsigned short* dst = wsp + (isK ? WKF_OFF : WQF_OFF);
    for (int i = threadIdx.x; i < 4 * 129; i += 256) {
      int r = i / 129, q = i - r * 129;
      int o = ob + r, k = q * 2;
      float2 w2 = *(const float2*)(w + o * 258 + k);
      int g = o >> 5, col = o & 31;
      int ks = k >> 4, hi = (k >> 3) & 1, j = k & 7;
      uint32_t pk = (uint32_t)f2bf(w2.x) | ((uint32_t)f2bf(w2.y) << 16);
      *(uint32_t*)(dst + (((g * 18 + ks) * 64 + hi * 32 + col) << 3) + j) = pk;
    }
    for (int i = threadIdx.x; i < 4 * 30; i += 256) {
      int r = i / 30, kk = 258 + (i - r * 30);
      int o = ob + r;
      int g = o >> 5, col = o & 31;
      int ks = kk >> 4, hi = (kk >> 3) & 1, j = kk & 7;
      dst[(((g * 18 + ks) * 64 + hi * 32 + col) << 3) + j] =
          (kk == 258) ? f2bf(bb[o]) : (unsigned short)0;
    }
  } else {
    int idx = (bid - 512) * 256 + threadIdx.x;
    int fc = idx & 15, m = (idx >> 4) & 63, o = idx >> 10;
    const f32x4* wo = (const f32x4*)(wout + o * 256 + fc * 16);
    const f32x4* vm = (const f32x4*)(v + m * 256 + fc * 16);
    float s = 0.f;
#pragma unroll
    for (int f = 0; f < 4; ++f) {
      f32x4 a = wo[f], bvv = vm[f];
      s += a[0]*bvv[0] + a[1]*bvv[1] + a[2]*bvv[2] + a[3]*bvv[3];
    }
    s += __shfl_xor(s, 1, 64);
    s += __shfl_xor(s, 2, 64);
    s += __shfl_xor(s, 4, 64);
    s += __shfl_xor(s, 8, 64);
    if (fc == 0) wsp[WVP_OFF + o * 64 + m] = f2bf(s);
  }
}

// =====================================================================
// fused: 64 px/block, 256 blocks, 16 waves, 1 block/CU.
// R11: (a) staging reverted to c-major mapping -> each wave load is 64
// consecutive floats (256B coalesced); 8-way LDS write conflict accepted
// (measured-trivial). (b) barrier moved from before k-loop to after it:
// k-MFMAs don't read qbar, so slow-norm waves no longer gate the k-loop.
// =====================================================================
#define KP 296   // xp row stride in shorts
#define QS 66    // qbar row stride (floats)
#define AT 72    // attnM row stride (shorts)

__global__ __launch_bounds__(1024, 4) void fused_kernel(
    const float* __restrict__ x, const float* __restrict__ pos,
    const unsigned short* __restrict__ wsp, const float* __restrict__ bout,
    float* __restrict__ out) {
  __shared__ __align__(16) unsigned short aBuf[3 * 32 * 512];  // 98304 B
  __shared__ __align__(16) unsigned short xp[64 * KP];         // 37888 B
  __shared__ __align__(16) float qbarL[16 * QS];               // 4224 B
  __shared__ __align__(16) unsigned short attnM[64 * AT];      // 9216 B
  __shared__ float boutL[256];                                 // 1024 B

  const int tid = threadIdx.x;
  const int lane = tid & 63;
  const int wid = __builtin_amdgcn_readfirstlane(tid >> 6);
  const int px = lane & 31, q2 = lane >> 5;
  const int P0 = blockIdx.x * 64;
  const int b = P0 >> 12, s0 = P0 & 4095;

#define ISSUE(wb, ks_) do {                                              \
    int _sl = (ks_) % 3;                                                 \
    dma16(wb + ((2 * wid) * 18 + (ks_)) * 512 + lane * 8,                \
          &aBuf[_sl * 16384 + (2 * wid) * 512]);                         \
    dma16(wb + ((2 * wid + 1) * 18 + (ks_)) * 512 + lane * 8,            \
          &aBuf[_sl * 16384 + (2 * wid + 1) * 512]);                     \
  } while (0)

  // q-phase DMA warm-up: latency hidden behind the staging phase.
  ISSUE((wsp + WQF_OFF), 0);
  ISSUE((wsp + WQF_OFF), 1);

  // ---- stage xp[p][c]: c-major mapping — one dcol per wave-instruction,
  // lanes sweep 64 consecutive pixels -> 256B coalesced global reads.
  uint32_t* xp32 = (uint32_t*)xp;
  for (int i = tid; i < 64 * 152; i += 1024) {
    int p = i & 63, dcol = i >> 6;   // dcol = tid>>6 (+16 per iter)
    if (dcol < 148) {
      int c0 = dcol * 2;
      float v0, v1;
      if (c0 < 256) {
        v0 = x[(b * 256 + c0) * 4096 + s0 + p];
        v1 = x[(b * 256 + c0 + 1) * 4096 + s0 + p];
      } else if (c0 == 256) {
        v0 = pos[s0 + p];
        v1 = pos[4096 + s0 + p];
      } else {
        v0 = (c0 == 258) ? 1.0f : 0.0f;   // bias channel
        v1 = 0.0f;
      }
      xp32[p * 148 + dcol] = (uint32_t)f2bf(v0) | ((uint32_t)f2bf(v1) << 16);
    }
  }
  if (tid < 256) boutL[tid] = bout[tid];
  for (int i = tid; i < 16 * QS; i += 1024) qbarL[i] = 0.f;
  __syncthreads();

#define COMPUTEA(ks_, b0_, b1_) do {                                     \
    int _sl = (ks_) % 3;                                                 \
    bf16x8 _a0 = *(const bf16x8*)&aBuf[_sl * 16384 + (2 * wid) * 512 + lane * 8];     \
    bf16x8 _a1 = *(const bf16x8*)&aBuf[_sl * 16384 + (2 * wid + 1) * 512 + lane * 8]; \
    acc00 = __builtin_amdgcn_mfma_f32_32x32x16_bf16(_a0, b0_, acc00, 0, 0, 0); \
    acc01 = __builtin_amdgcn_mfma_f32_32x32x16_bf16(_a0, b1_, acc01, 0, 0, 0); \
    acc10 = __builtin_amdgcn_mfma_f32_32x32x16_bf16(_a1, b0_, acc10, 0, 0, 0); \
    acc11 = __builtin_amdgcn_mfma_f32_32x32x16_bf16(_a1, b1_, acc11, 0, 0, 0); \
  } while (0)

// vmcnt algebra (holds whether or not the 2 warm-up slices drained):
// iter ks: issue +2 -> own outstanding 6 (or less); wait vmcnt(4) drains
// the 2 oldest = slice ks. Tail peeled to vmcnt(2)/(0).
#define PHASE(wb) do {                                                   \
    _Pragma("unroll 4")                                                  \
    for (int ks = 0; ks < 16; ++ks) {                                    \
      bf16x8 _b0 = *(const bf16x8*)&xp[px * KP + ks * 16 + q2 * 8];      \
      bf16x8 _b1 = *(const bf16x8*)&xp[(32 + px) * KP + ks * 16 + q2 * 8]; \
      ISSUE(wb, ks + 2);                                                 \
      asm volatile("s_waitcnt vmcnt(4)" ::: "memory");                   \
      COMPUTEA(ks, _b0, _b1);                                            \
    }                                                                    \
    {                                                                    \
      bf16x8 _b0 = *(const bf16x8*)&xp[px * KP + 16 * 16 + q2 * 8];      \
      bf16x8 _b1 = *(const bf16x8*)&xp[(32 + px) * KP + 16 * 16 + q2 * 8]; \
      asm volatile("s_waitcnt vmcnt(2)" ::: "memory");                   \
      COMPUTEA(16, _b0, _b1);                                            \
    }                                                                    \
    {                                                                    \
      bf16x8 _b0 = *(const bf16x8*)&xp[px * KP + 17 * 16 + q2 * 8];      \
      bf16x8 _b1 = *(const bf16x8*)&xp[(32 + px) * KP + 17 * 16 + q2 * 8]; \
      asm volatile("s_waitcnt vmcnt(0)" ::: "memory");                   \
      COMPUTEA(17, _b0, _b1);                                            \
    }                                                                    \
  } while (0)

  // ================= q phase =================
  f32x16 acc00 = (f32x16)0.f, acc01 = (f32x16)0.f,
         acc10 = (f32x16)0.f, acc11 = (f32x16)0.f;
  PHASE((wsp + WQF_OFF));

  // k-phase DMA warm-up: latency hidden behind the norm section.
  ISSUE((wsp + WKF_OFF), 0);
  ISSUE((wsp + WKF_OFF), 1);

  // normalize per m; accumulate qbar partials (LDS atomics, no barrier —
  // the post-k-loop barrier protects qbarL readers)
  {
    float qsum[2][8];
#pragma unroll
    for (int nt = 0; nt < 2; ++nt)
#pragma unroll
      for (int r = 0; r < 8; ++r) qsum[nt][r] = 0.f;
#pragma unroll
    for (int ot = 0; ot < 2; ++ot) {
#pragma unroll
      for (int nt = 0; nt < 2; ++nt) {
        const f32x16 a = ot ? (nt ? acc11 : acc10) : (nt ? acc01 : acc00);
        float s20 = 0.f, s21 = 0.f;
#pragma unroll
        for (int r = 0; r < 8; ++r) {
          s20 = fmaf(a[r], a[r], s20);
          s21 = fmaf(a[r + 8], a[r + 8], s21);
        }
        s20 += __shfl_xor(s20, 32, 64);
        s21 += __shfl_xor(s21, 32, 64);
        float i0 = 1.0f / fmaxf(sqrtf(s20), EPSN);
        float i1 = 1.0f / fmaxf(sqrtf(s21), EPSN);
#pragma unroll
        for (int r = 0; r < 8; ++r) qsum[nt][r] += a[r] * i0 + a[r + 8] * i1;
      }
    }
#pragma unroll
    for (int nt = 0; nt < 2; ++nt)
#pragma unroll
      for (int r = 0; r < 8; ++r) {
        int j = (r & 3) + ((r >> 2) << 3) + (q2 << 2);
        atomicAdd(&qbarL[j * QS + nt * 32 + px], qsum[nt][r] * (1.0f / 64.0f));
      }
  }

  // ================= k phase (no barrier before it) =================
  acc00 = (f32x16)0.f; acc01 = (f32x16)0.f;
  acc10 = (f32x16)0.f; acc11 = (f32x16)0.f;
  PHASE((wsp + WKF_OFF));

  __syncthreads();  // qbar atomics (all waves) complete before reads below

  {
    float qb[2][8];
#pragma unroll
    for (int nt = 0; nt < 2; ++nt)
#pragma unroll
      for (int r = 0; r < 8; ++r) {
        int j = (r & 3) + ((r >> 2) << 3) + (q2 << 2);
        qb[nt][r] = qbarL[j * QS + nt * 32 + px];
      }
#pragma unroll
    for (int ot = 0; ot < 2; ++ot) {
#pragma unroll
      for (int nt = 0; nt < 2; ++nt) {
        const f32x16 a = ot ? (nt ? acc11 : acc10) : (nt ? acc01 : acc00);
        float s20 = 0.f, s21 = 0.f, sp0 = 0.f, sp1 = 0.f;
#pragma unroll
        for (int r = 0; r < 8; ++r) {
          s20 = fmaf(a[r], a[r], s20);         sp0 = fmaf(qb[nt][r], a[r], sp0);
          s21 = fmaf(a[r + 8], a[r + 8], s21); sp1 = fmaf(qb[nt][r], a[r + 8], sp1);
        }
        s20 += __shfl_xor(s20, 32, 64);
        s21 += __shfl_xor(s21, 32, 64);
        sp0 += __shfl_xor(sp0, 32, 64);
        sp1 += __shfl_xor(sp1, 32, 64);
        if (q2 == 0) {
          int m0 = wid * 4 + ot * 2;
          attnM[(nt * 32 + px) * AT + m0]     = f2bf(sp0 / fmaxf(sqrtf(s20), EPSN));
          attnM[(nt * 32 + px) * AT + m0 + 1] = f2bf(sp1 / fmaxf(sqrtf(s21), EPSN));
        }
      }
    }
  }
  __syncthreads();

  // ================= epilogue: out = x + bout + WVt @ attn =================
  {
    const int otile = wid >> 1, pxt = wid & 1;
    f32x16 e = (f32x16)0.f;
    const unsigned short* wv = wsp + WVP_OFF + (otile * 32 + px) * 64 + q2 * 8;
    const unsigned short* ab = &attnM[(pxt * 32 + px) * AT + q2 * 8];
#pragma unroll
    for (int ks = 0; ks < 4; ++ks) {
      bf16x8 av = *(const bf16x8*)(wv + ks * 16);
      bf16x8 bv = *(const bf16x8*)(ab + ks * 16);
      e = __builtin_amdgcn_mfma_f32_32x32x16_bf16(av, bv, e, 0, 0, 0);
    }
#pragma unroll
    for (int r = 0; r < 16; ++r) {
      const int o = otile * 32 + (r & 3) + ((r >> 2) << 3) + (q2 << 2);
      const int p = pxt * 32 + px;
      const int gi = (b * 256 + o) * 4096 + s0 + p;
      out[gi] = x[gi] + boutL[o] + e[r];
    }
  }
#undef PHASE
#undef COMPUTEA
#undef ISSUE
}

// =====================================================================
extern "C" void kernel_launch(void* const* d_in, const int* in_sizes, int n_in,
                              void* d_out, int out_size, void* d_ws, size_t ws_size,
                              hipStream_t stream) {
  const float* x    = (const float*)d_in[0];
  const float* pos  = (const float*)d_in[1];
  const float* wq   = (const float*)d_in[2];
  const float* bq   = (const float*)d_in[3];
  const float* wk   = (const float*)d_in[4];
  const float* bk   = (const float*)d_in[5];
  const float* v    = (const float*)d_in[6];
  const float* wout = (const float*)d_in[7];
  const float* bout = (const float*)d_in[8];
  float* out = (float*)d_out;
  unsigned short* wsp = (unsigned short*)d_ws;

  hipLaunchKernelGGL(prep_kernel, dim3(1536), dim3(256), 0, stream,
                     wq, bq, wk, bk, v, wout, wsp);
  hipLaunchKernelGGL(fused_kernel, dim3(256), dim3(1024), 0, stream,
                     x, pos, wsp, bout, out);
}